// Round 2
// baseline (650.987 us; speedup 1.0000x reference)
//
#include <hip/hip_runtime.h>
#include <hip/hip_fp16.h>

// NNUE forward: out = MLP(clip(concat(Wf@w_in^T+b, Bf@w_in^T+b)))
// Big GEMM: M=8192 (white rows 0..4095, black 4096..8191), N=256, K=40960.
// Memory-bound: 1.38 GB mandatory reads -> ~220us floor at 6.3 TB/s.
// fp16 MFMA (16x16x32), f32 accumulate; f32->f16 cvt fused into LDS staging.
//
// v2: BN=256 (whole w_in panel per block) eliminates the duplicate A-read of
// the BN=128 grid; KS=4 K-split restores 256 blocks (1 per CU). 1024 thr.

#define FEAT 40960
#define PSTRIDE (8192ull * 256ull)

using floatx4 = __attribute__((ext_vector_type(4))) float;
using half8   = __attribute__((ext_vector_type(8))) _Float16;
using half4   = __attribute__((ext_vector_type(4))) _Float16;

// ---------------------------------------------------------------------------
// Primary GEMM: BM=128, BN=256, BK=64, 1024 threads = 16 waves (4M x 4N),
// wave tile 32x64. Reg-staged f32 loads -> cvt f16 -> XOR-swizzled LDS -> MFMA.
// grid = 64 * KS blocks (KS=4 -> 256 blocks, 1/CU). A read exactly once.
// ---------------------------------------------------------------------------
__global__ __launch_bounds__(1024, 4) void nnue_gemm_bn256(
    const float* __restrict__ white, const float* __restrict__ black,
    const float* __restrict__ w_in, float* __restrict__ P, int KS)
{
    __shared__ __align__(16) _Float16 As[2][128 * 64];   // 32 KB
    __shared__ __align__(16) _Float16 Ws[2][256 * 64];   // 64 KB

    const int tid  = threadIdx.x;
    const int lane = tid & 63;
    const int wave = tid >> 6;    // 0..15
    const int wm   = wave >> 2;   // 0..3 (M)
    const int wn   = wave & 3;    // 0..3 (N)

    const int bid = blockIdx.x;
    const int mb  = bid & 63;
    const int ks  = bid >> 6;

    const float* Abase = (mb < 32)
        ? (white + (size_t)mb * 128 * FEAT)
        : (black + (size_t)(mb - 32) * 128 * FEAT);

    const int kchunk = FEAT / KS;
    const int k0     = ks * kchunk;
    const int nsteps = kchunk / 64;   // KS=4 -> 160 (even)

    // staging: A tile 128x64 f32 = 2048 float4 (2/thread), W 256x64 = 4096 (4/thread)
    const int c4   = tid & 15;        // float4 column
    const int row0 = tid >> 4;        // 0..63

    // fragment geometry (mfma_f32_16x16x32_f16, m89-verified):
    // operand: lane reads row (lane&15), k-halves (lane>>4)*8..+7 (16B)
    // C/D:     row = (lane>>4)*4 + reg, col = lane&15
    const int frow  = lane & 15;
    const int fhi   = lane >> 4;
    const int swz_r = (frow & 7) << 4;

    floatx4 acc[2][4];
    const floatx4 zero = {0.f, 0.f, 0.f, 0.f};
#pragma unroll
    for (int m = 0; m < 2; ++m)
#pragma unroll
        for (int n = 0; n < 4; ++n) acc[m][n] = zero;

    floatx4 ra0[2], rw0[4], ra1[2], rw1[4];

    auto issue = [&](int kglob, floatx4 (&ra)[2], floatx4 (&rw)[4]) {
#pragma unroll
        for (int i = 0; i < 2; ++i)
            ra[i] = *reinterpret_cast<const floatx4*>(
                Abase + (size_t)(row0 + 64 * i) * FEAT + kglob + c4 * 4);
#pragma unroll
        for (int i = 0; i < 4; ++i)
            rw[i] = *reinterpret_cast<const floatx4*>(
                w_in + (size_t)(row0 + 64 * i) * FEAT + kglob + c4 * 4);
    };

    auto cvtStore = [&](int buf, floatx4 (&ra)[2], floatx4 (&rw)[4]) {
        const int swz = (row0 & 7) << 4;           // rows row0+64i share low bits
        const int off = (c4 * 8) ^ swz;
#pragma unroll
        for (int i = 0; i < 2; ++i) {
            half4 h;
#pragma unroll
            for (int j = 0; j < 4; ++j) h[j] = (_Float16)ra[i][j];  // RNE
            *reinterpret_cast<half4*>(
                reinterpret_cast<char*>(&As[buf][0]) + (row0 + 64 * i) * 128 + off) = h;
        }
#pragma unroll
        for (int i = 0; i < 4; ++i) {
            half4 h;
#pragma unroll
            for (int j = 0; j < 4; ++j) h[j] = (_Float16)rw[i][j];
            *reinterpret_cast<half4*>(
                reinterpret_cast<char*>(&Ws[buf][0]) + (row0 + 64 * i) * 128 + off) = h;
        }
    };

    auto mfmaStep = [&](int buf) {
#pragma unroll
        for (int kk = 0; kk < 2; ++kk) {
            const int kb = (kk * 64 + fhi * 16) ^ swz_r;
            half8 af[2], bf[4];
#pragma unroll
            for (int m = 0; m < 2; ++m) {
                const int r = wm * 32 + m * 16 + frow;
                af[m] = *reinterpret_cast<const half8*>(
                    reinterpret_cast<const char*>(&As[buf][0]) + r * 128 + kb);
            }
#pragma unroll
            for (int n = 0; n < 4; ++n) {
                const int r = wn * 64 + n * 16 + frow;
                bf[n] = *reinterpret_cast<const half8*>(
                    reinterpret_cast<const char*>(&Ws[buf][0]) + r * 128 + kb);
            }
#pragma unroll
            for (int m = 0; m < 2; ++m)
#pragma unroll
                for (int n = 0; n < 4; ++n)
                    acc[m][n] = __builtin_amdgcn_mfma_f32_16x16x32_f16(af[m], bf[n], acc[m][n], 0, 0, 0);
        }
    };

    issue(k0, ra0, rw0);
    for (int t = 0; t < nsteps; t += 2) {
        if (t + 1 < nsteps) issue(k0 + (t + 1) * 64, ra1, rw1);
        cvtStore(0, ra0, rw0);
        __syncthreads();
        mfmaStep(0);
        if (t + 2 < nsteps) issue(k0 + (t + 2) * 64, ra0, rw0);
        cvtStore(1, ra1, rw1);
        __syncthreads();
        mfmaStep(1);
    }

    // epilogue: partial C (pre-bias, pre-clip) to workspace
    float* Pb = P + (size_t)ks * PSTRIDE + (size_t)mb * 128 * 256;
#pragma unroll
    for (int m = 0; m < 2; ++m)
#pragma unroll
        for (int n = 0; n < 4; ++n)
#pragma unroll
            for (int r = 0; r < 4; ++r) {
                const int row = wm * 32 + m * 16 + fhi * 4 + r;
                const int col = wn * 64 + n * 16 + frow;
                Pb[(size_t)row * 256 + col] = acc[m][n][r];
            }
}

// ---------------------------------------------------------------------------
// Fallback GEMM (proven r1 path): BM=128, BN=128, BK=64, 512 threads.
// Used when ws_size < 32 MB.
// ---------------------------------------------------------------------------
__global__ __launch_bounds__(512, 2) void nnue_gemm(
    const float* __restrict__ white, const float* __restrict__ black,
    const float* __restrict__ w_in, float* __restrict__ P, int KS)
{
    __shared__ __align__(16) _Float16 As[2][128 * 64];
    __shared__ __align__(16) _Float16 Ws[2][128 * 64];

    const int tid  = threadIdx.x;
    const int lane = tid & 63;
    const int wave = tid >> 6;
    const int wm   = wave >> 2;
    const int wn   = wave & 3;

    const int bid = blockIdx.x;
    const int mb  = bid / (2 * KS);
    const int rem = bid % (2 * KS);
    const int ks  = rem >> 1;
    const int nb  = rem & 1;

    const float* Abase = (mb < 32)
        ? (white + (size_t)mb * 128 * FEAT)
        : (black + (size_t)(mb - 32) * 128 * FEAT);
    const float* Wbase = w_in + (size_t)nb * 128 * FEAT;

    const int kchunk = FEAT / KS;
    const int k0     = ks * kchunk;
    const int nsteps = kchunk / 64;

    const int c4    = tid & 15;
    const int row0  = tid >> 4;
    const int swz_w = (row0 & 7) << 4;
    const int frow  = lane & 15;
    const int fhi   = lane >> 4;
    const int swz_r = (frow & 7) << 4;

    floatx4 acc[4][2];
    const floatx4 zero = {0.f, 0.f, 0.f, 0.f};
#pragma unroll
    for (int m = 0; m < 4; ++m)
#pragma unroll
        for (int n = 0; n < 2; ++n) acc[m][n] = zero;

    floatx4 ra0[4], rw0[4], ra1[4], rw1[4];

    auto issue = [&](int kglob, floatx4 (&ra)[4], floatx4 (&rw)[4]) {
#pragma unroll
        for (int i = 0; i < 4; ++i) {
            const int row = row0 + 32 * i;
            ra[i] = *reinterpret_cast<const floatx4*>(Abase + (size_t)row * FEAT + kglob + c4 * 4);
            rw[i] = *reinterpret_cast<const floatx4*>(Wbase + (size_t)row * FEAT + kglob + c4 * 4);
        }
    };

    auto cvtStore = [&](int buf, floatx4 (&ra)[4], floatx4 (&rw)[4]) {
#pragma unroll
        for (int i = 0; i < 4; ++i) {
            const int row = row0 + 32 * i;
            const int off = row * 128 + ((c4 * 8) ^ swz_w);
            half4 ha, hw;
#pragma unroll
            for (int j = 0; j < 4; ++j) {
                ha[j] = (_Float16)ra[i][j];
                hw[j] = (_Float16)rw[i][j];
            }
            *reinterpret_cast<half4*>(reinterpret_cast<char*>(&As[buf][0]) + off) = ha;
            *reinterpret_cast<half4*>(reinterpret_cast<char*>(&Ws[buf][0]) + off) = hw;
        }
    };

    auto mfmaStep = [&](int buf) {
#pragma unroll
        for (int kk = 0; kk < 2; ++kk) {
            const int kb = (kk * 64 + fhi * 16) ^ swz_r;
            half8 af[4], bf[2];
#pragma unroll
            for (int m = 0; m < 4; ++m) {
                const int r = wm * 64 + m * 16 + frow;
                af[m] = *reinterpret_cast<const half8*>(
                    reinterpret_cast<const char*>(&As[buf][0]) + r * 128 + kb);
            }
#pragma unroll
            for (int n = 0; n < 2; ++n) {
                const int r = wn * 32 + n * 16 + frow;
                bf[n] = *reinterpret_cast<const half8*>(
                    reinterpret_cast<const char*>(&Ws[buf][0]) + r * 128 + kb);
            }
#pragma unroll
            for (int m = 0; m < 4; ++m)
#pragma unroll
                for (int n = 0; n < 2; ++n)
                    acc[m][n] = __builtin_amdgcn_mfma_f32_16x16x32_f16(af[m], bf[n], acc[m][n], 0, 0, 0);
        }
    };

    issue(k0, ra0, rw0);
    for (int t = 0; t < nsteps; t += 2) {
        if (t + 1 < nsteps) issue(k0 + (t + 1) * 64, ra1, rw1);
        cvtStore(0, ra0, rw0);
        __syncthreads();
        mfmaStep(0);
        if (t + 2 < nsteps) issue(k0 + (t + 2) * 64, ra0, rw0);
        cvtStore(1, ra1, rw1);
        __syncthreads();
        mfmaStep(1);
    }

    float* Pb = P + (size_t)ks * PSTRIDE + (size_t)mb * 128 * 256 + nb * 128;
#pragma unroll
    for (int m = 0; m < 4; ++m)
#pragma unroll
        for (int n = 0; n < 2; ++n)
#pragma unroll
            for (int r = 0; r < 4; ++r) {
                const int row = wm * 64 + m * 16 + fhi * 4 + r;
                const int col = wn * 32 + n * 16 + frow;
                Pb[(size_t)row * 256 + col] = acc[m][n][r];
            }
}

// ---------------------------------------------------------------------------
// Tail: reduce K-split partials + b_in + clip -> x[.,512], then the 3 tiny
// layers. One block per 32 batch rows.
// ---------------------------------------------------------------------------
__global__ __launch_bounds__(256) void nnue_tail(
    const float* __restrict__ P, int KS,
    const float* __restrict__ b_in,
    const float* __restrict__ w_h1, const float* __restrict__ b_h1,
    const float* __restrict__ w_h2, const float* __restrict__ b_h2,
    const float* __restrict__ w_out, const float* __restrict__ b_out,
    float* __restrict__ out)
{
    __shared__ float xs[32][512];
    __shared__ float w1[32][513];
    __shared__ float w2[32][33];
    __shared__ float h1[32][33];
    __shared__ float h2[32][33];
    __shared__ float wo[32];

    const int tid = threadIdx.x;
    const int b0  = blockIdx.x * 32;

    for (int i = tid; i < 32 * 512; i += 256) w1[i >> 9][i & 511] = w_h1[i];
    for (int i = tid; i < 32 * 32; i += 256)  w2[i >> 5][i & 31]  = w_h2[i];
    if (tid < 32) wo[tid] = w_out[tid];

    for (int i = tid; i < 32 * 512; i += 256) {
        const int r = i >> 9, c = i & 511;
        const int persp = c >> 8, n = c & 255;
        const size_t prow = (size_t)(b0 + r) + (persp ? 4096u : 0u);
        float v = 0.f;
        for (int s = 0; s < KS; ++s) v += P[(s * PSTRIDE) + prow * 256 + n];
        v += b_in[n];
        xs[r][c] = fminf(fmaxf(v, 0.f), 1.f);
    }
    __syncthreads();

    for (int p = tid; p < 32 * 32; p += 256) {
        const int o = p & 31, r = p >> 5;
        float a = b_h1[o];
        for (int j = 0; j < 512; ++j) a += xs[r][j] * w1[o][j];
        h1[r][o] = fminf(fmaxf(a, 0.f), 1.f);
    }
    __syncthreads();

    for (int p = tid; p < 32 * 32; p += 256) {
        const int o = p & 31, r = p >> 5;
        float a = b_h2[o];
        for (int j = 0; j < 32; ++j) a += h1[r][j] * w2[o][j];
        h2[r][o] = fminf(fmaxf(a, 0.f), 1.f);
    }
    __syncthreads();

    if (tid < 32) {
        float a = b_out[0];
        for (int j = 0; j < 32; ++j) a += h2[tid][j] * wo[j];
        out[b0 + tid] = a;
    }
}

// ---------------------------------------------------------------------------
// Emergency fallback (ws too small for any split): slow but correct.
// ---------------------------------------------------------------------------
__global__ __launch_bounds__(256) void nnue_naive(
    const float* __restrict__ white, const float* __restrict__ black,
    const float* __restrict__ w_in, const float* __restrict__ b_in,
    const float* __restrict__ w_h1, const float* __restrict__ b_h1,
    const float* __restrict__ w_h2, const float* __restrict__ b_h2,
    const float* __restrict__ w_out, const float* __restrict__ b_out,
    float* __restrict__ out)
{
    __shared__ float feat[4096];
    __shared__ float xs[512];
    __shared__ float h1s[32];
    __shared__ float h2s[32];
    const int b = blockIdx.x, tid = threadIdx.x;
    float acc0 = 0.f, acc1 = 0.f;
    for (int c = 0; c < FEAT; c += 2048) {
        for (int i = tid; i < 2048; i += 256) {
            feat[i]        = white[(size_t)b * FEAT + c + i];
            feat[2048 + i] = black[(size_t)b * FEAT + c + i];
        }
        __syncthreads();
        const float* wr = w_in + (size_t)tid * FEAT + c;
        for (int k = 0; k < 2048; ++k) {
            const float w = wr[k];
            acc0 += feat[k] * w;
            acc1 += feat[2048 + k] * w;
        }
        __syncthreads();
    }
    xs[tid]       = fminf(fmaxf(acc0 + b_in[tid], 0.f), 1.f);
    xs[256 + tid] = fminf(fmaxf(acc1 + b_in[tid], 0.f), 1.f);
    __syncthreads();
    if (tid < 32) {
        float a = b_h1[tid];
        for (int j = 0; j < 512; ++j) a += xs[j] * w_h1[tid * 512 + j];
        h1s[tid] = fminf(fmaxf(a, 0.f), 1.f);
    }
    __syncthreads();
    if (tid < 32) {
        float a = b_h2[tid];
        for (int j = 0; j < 32; ++j) a += h1s[j] * w_h2[tid * 32 + j];
        h2s[tid] = fminf(fmaxf(a, 0.f), 1.f);
    }
    __syncthreads();
    if (tid == 0) {
        float a = b_out[0];
        for (int j = 0; j < 32; ++j) a += h2s[j] * w_out[j];
        out[b] = a;
    }
}

extern "C" void kernel_launch(void* const* d_in, const int* in_sizes, int n_in,
                              void* d_out, int out_size, void* d_ws, size_t ws_size,
                              hipStream_t stream)
{
    const float* white = (const float*)d_in[0];
    const float* black = (const float*)d_in[1];
    const float* w_in  = (const float*)d_in[2];
    const float* b_in  = (const float*)d_in[3];
    const float* w_h1  = (const float*)d_in[4];
    const float* b_h1  = (const float*)d_in[5];
    const float* w_h2  = (const float*)d_in[6];
    const float* b_h2  = (const float*)d_in[7];
    const float* w_out = (const float*)d_in[8];
    const float* b_out = (const float*)d_in[9];
    float* out = (float*)d_out;
    float* P   = (float*)d_ws;

    const size_t bytesPerSplit = PSTRIDE * sizeof(float);   // 8 MB

    if (ws_size >= 4 * bytesPerSplit) {
        // Primary: BN=256, KS=4 -> 256 blocks (1/CU), A read exactly once.
        nnue_gemm_bn256<<<dim3(64 * 4), 1024, 0, stream>>>(white, black, w_in, P, 4);
        nnue_tail<<<dim3(128), 256, 0, stream>>>(P, 4, b_in, w_h1, b_h1,
                                                 w_h2, b_h2, w_out, b_out, out);
    } else if (ws_size >= 2 * bytesPerSplit) {
        nnue_gemm<<<dim3(64 * 2 * 2), 512, 0, stream>>>(white, black, w_in, P, 2);
        nnue_tail<<<dim3(128), 256, 0, stream>>>(P, 2, b_in, w_h1, b_h1,
                                                 w_h2, b_h2, w_out, b_out, out);
    } else if (ws_size >= bytesPerSplit) {
        nnue_gemm<<<dim3(64 * 2 * 1), 512, 0, stream>>>(white, black, w_in, P, 1);
        nnue_tail<<<dim3(128), 256, 0, stream>>>(P, 1, b_in, w_h1, b_h1,
                                                 w_h2, b_h2, w_out, b_out, out);
    } else {
        nnue_naive<<<4096, 256, 0, stream>>>(white, black, w_in, b_in, w_h1, b_h1,
                                             w_h2, b_h2, w_out, b_out, out);
    }
}

// Round 3
// 417.990 us; speedup vs baseline: 1.5574x; 1.5574x over previous
//
#include <hip/hip_runtime.h>
#include <hip/hip_fp16.h>

// NNUE forward: out = MLP(clip(concat(Wf@w_in^T+b, Bf@w_in^T+b)))
// Big GEMM: M=8192, N=256, K=40960. Memory-bound: 1.38 GB mandatory reads
// -> ~220us floor at 6.3 TB/s. fp16 MFMA 16x16x32, f32 accumulate.
//
// v3: BN=256 kept (traffic win confirmed by r2 counters: 1.29 GB), but fixed
// the r2 latency collapse: 512-thread blocks (VGPR cap 128, prefetch regs
// stay live), KS=8 -> 512 blocks = 2 blocks/CU (implicit cross-block overlap,
// 24 KB LDS single-buffer), BK=32. P partials f16 (32 MB ws) or f32 (64 MB).

#define FEAT 40960
#define PSTRIDE (8192ull * 256ull)
#define KSPLIT 8
#define KCHUNK (FEAT / KSPLIT)   // 5120
#define NSTEPS (KCHUNK / 32)     // 160

using floatx4 = __attribute__((ext_vector_type(4))) float;
using half8   = __attribute__((ext_vector_type(8))) _Float16;
using half4   = __attribute__((ext_vector_type(4))) _Float16;

// ---------------------------------------------------------------------------
// GEMM: BM=128, BN=256, BK=32. 512 threads = 8 waves (2M x 4N), wave tile
// 64x64 (acc 4x4 = 64 VGPR). Reg-staged f32 loads (single set, issued after
// consumption -> in flight across MFMA phase) -> cvt f16 -> swizzled LDS.
// grid = 64 mb x 8 ks = 512 blocks, 2/CU.
// ---------------------------------------------------------------------------
template <typename PT>
__global__ __launch_bounds__(512, 4) void nnue_gemm8(
    const float* __restrict__ white, const float* __restrict__ black,
    const float* __restrict__ w_in, PT* __restrict__ P)
{
    __shared__ __align__(16) _Float16 As[128 * 32];   // 8 KB
    __shared__ __align__(16) _Float16 Ws[256 * 32];   // 16 KB

    const int tid  = threadIdx.x;
    const int lane = tid & 63;
    const int wave = tid >> 6;    // 0..7
    const int wm   = wave >> 2;   // 0..1 (M)
    const int wn   = wave & 3;    // 0..3 (N)

    const int mb = blockIdx.x & 63;
    const int ks = blockIdx.x >> 6;

    const float* Abase = (mb < 32)
        ? (white + (size_t)mb * 128 * FEAT)
        : (black + (size_t)(mb - 32) * 128 * FEAT);
    const int k0 = ks * KCHUNK;

    // staging: A tile 128x32 f32 = 1024 float4 (2/thread), W 256x32 = 2048 (4/thread)
    const int c4    = tid & 7;          // float4 column (8 per row)
    const int row0  = tid >> 3;         // 0..63
    const int swz_w = (row0 & 3) << 4;  // XOR swizzle, 16B granules in 64B row

    // fragment geometry (mfma_f32_16x16x32_f16, m89-verified):
    // operand: lane reads row (lane&15), k-halves (lane>>4)*8..+7 (16B)
    // C/D:     row = (lane>>4)*4 + reg, col = lane&15
    const int frow  = lane & 15;
    const int fhi   = lane >> 4;
    const int swz_r = (frow & 3) << 4;

    floatx4 acc[4][4];
    const floatx4 zero = {0.f, 0.f, 0.f, 0.f};
#pragma unroll
    for (int m = 0; m < 4; ++m)
#pragma unroll
        for (int n = 0; n < 4; ++n) acc[m][n] = zero;

    floatx4 ra[2], rw[4];

    auto issue = [&](int kglob) {
#pragma unroll
        for (int i = 0; i < 2; ++i)
            ra[i] = *reinterpret_cast<const floatx4*>(
                Abase + (size_t)(row0 + 64 * i) * FEAT + kglob + c4 * 4);
#pragma unroll
        for (int i = 0; i < 4; ++i)
            rw[i] = *reinterpret_cast<const floatx4*>(
                w_in + (size_t)(row0 + 64 * i) * FEAT + kglob + c4 * 4);
    };

    auto cvtStore = [&]() {
        const int off = (c4 * 8) ^ swz_w;
#pragma unroll
        for (int i = 0; i < 2; ++i) {
            half4 h;
#pragma unroll
            for (int j = 0; j < 4; ++j) h[j] = (_Float16)ra[i][j];   // RNE
            *reinterpret_cast<half4*>(
                reinterpret_cast<char*>(&As[0]) + (row0 + 64 * i) * 64 + off) = h;
        }
#pragma unroll
        for (int i = 0; i < 4; ++i) {
            half4 h;
#pragma unroll
            for (int j = 0; j < 4; ++j) h[j] = (_Float16)rw[i][j];
            *reinterpret_cast<half4*>(
                reinterpret_cast<char*>(&Ws[0]) + (row0 + 64 * i) * 64 + off) = h;
        }
    };

    auto mfmaStep = [&]() {
        const int kb = (fhi * 16) ^ swz_r;
        half8 bf[4];
#pragma unroll
        for (int n = 0; n < 4; ++n) {
            const int r = wn * 64 + n * 16 + frow;
            bf[n] = *reinterpret_cast<const half8*>(
                reinterpret_cast<const char*>(&Ws[0]) + r * 64 + kb);
        }
#pragma unroll
        for (int m = 0; m < 4; ++m) {
            const int r = wm * 64 + m * 16 + frow;
            half8 af = *reinterpret_cast<const half8*>(
                reinterpret_cast<const char*>(&As[0]) + r * 64 + kb);
#pragma unroll
            for (int n = 0; n < 4; ++n)
                acc[m][n] = __builtin_amdgcn_mfma_f32_16x16x32_f16(af, bf[n], acc[m][n], 0, 0, 0);
        }
    };

    issue(k0);
    for (int t = 0; t < NSTEPS; ++t) {
        cvtStore();                              // waits on in-flight loads
        if (t + 1 < NSTEPS) issue(k0 + (t + 1) * 32);  // refill; flies over MFMA
        __syncthreads();                         // LDS tile visible
        mfmaStep();
        __syncthreads();                         // all reads done before rewrite
    }

    // epilogue: partial C (pre-bias, pre-clip) to workspace
    PT* Pb = P + (size_t)ks * PSTRIDE + (size_t)mb * 128 * 256;
#pragma unroll
    for (int m = 0; m < 4; ++m)
#pragma unroll
        for (int n = 0; n < 4; ++n)
#pragma unroll
            for (int r = 0; r < 4; ++r) {
                const int row = wm * 64 + m * 16 + fhi * 4 + r;
                const int col = wn * 64 + n * 16 + frow;
                Pb[(size_t)row * 256 + col] = (PT)acc[m][n][r];
            }
}

// ---------------------------------------------------------------------------
// Tail: reduce 8 K-split partials + b_in + clip -> x[.,512], then the 3 tiny
// layers. One block per 32 batch rows.
// ---------------------------------------------------------------------------
template <typename PT>
__global__ __launch_bounds__(256) void nnue_tail8(
    const PT* __restrict__ P,
    const float* __restrict__ b_in,
    const float* __restrict__ w_h1, const float* __restrict__ b_h1,
    const float* __restrict__ w_h2, const float* __restrict__ b_h2,
    const float* __restrict__ w_out, const float* __restrict__ b_out,
    float* __restrict__ out)
{
    __shared__ float xs[32][512];
    __shared__ float w1[32][513];
    __shared__ float w2[32][33];
    __shared__ float h1[32][33];
    __shared__ float h2[32][33];
    __shared__ float wo[32];

    const int tid = threadIdx.x;
    const int b0  = blockIdx.x * 32;

    for (int i = tid; i < 32 * 512; i += 256) w1[i >> 9][i & 511] = w_h1[i];
    for (int i = tid; i < 32 * 32; i += 256)  w2[i >> 5][i & 31]  = w_h2[i];
    if (tid < 32) wo[tid] = w_out[tid];

    for (int i = tid; i < 32 * 512; i += 256) {
        const int r = i >> 9, c = i & 511;
        const int persp = c >> 8, n = c & 255;
        const size_t prow = (size_t)(b0 + r) + (persp ? 4096u : 0u);
        float v = 0.f;
#pragma unroll
        for (int s = 0; s < KSPLIT; ++s)
            v += (float)P[(size_t)s * PSTRIDE + prow * 256 + n];
        v += b_in[n];
        xs[r][c] = fminf(fmaxf(v, 0.f), 1.f);
    }
    __syncthreads();

    for (int p = tid; p < 32 * 32; p += 256) {
        const int o = p & 31, r = p >> 5;
        float a = b_h1[o];
        for (int j = 0; j < 512; ++j) a += xs[r][j] * w1[o][j];
        h1[r][o] = fminf(fmaxf(a, 0.f), 1.f);
    }
    __syncthreads();

    for (int p = tid; p < 32 * 32; p += 256) {
        const int o = p & 31, r = p >> 5;
        float a = b_h2[o];
        for (int j = 0; j < 32; ++j) a += h1[r][j] * w2[o][j];
        h2[r][o] = fminf(fmaxf(a, 0.f), 1.f);
    }
    __syncthreads();

    if (tid < 32) {
        float a = b_out[0];
        for (int j = 0; j < 32; ++j) a += h2[tid][j] * wo[j];
        out[b0 + tid] = a;
    }
}

// ---------------------------------------------------------------------------
// Emergency fallback (ws too small for any split): slow but correct.
// ---------------------------------------------------------------------------
__global__ __launch_bounds__(256) void nnue_naive(
    const float* __restrict__ white, const float* __restrict__ black,
    const float* __restrict__ w_in, const float* __restrict__ b_in,
    const float* __restrict__ w_h1, const float* __restrict__ b_h1,
    const float* __restrict__ w_h2, const float* __restrict__ b_h2,
    const float* __restrict__ w_out, const float* __restrict__ b_out,
    float* __restrict__ out)
{
    __shared__ float feat[4096];
    __shared__ float xs[512];
    __shared__ float h1s[32];
    __shared__ float h2s[32];
    const int b = blockIdx.x, tid = threadIdx.x;
    float acc0 = 0.f, acc1 = 0.f;
    for (int c = 0; c < FEAT; c += 2048) {
        for (int i = tid; i < 2048; i += 256) {
            feat[i]        = white[(size_t)b * FEAT + c + i];
            feat[2048 + i] = black[(size_t)b * FEAT + c + i];
        }
        __syncthreads();
        const float* wr = w_in + (size_t)tid * FEAT + c;
        for (int k = 0; k < 2048; ++k) {
            const float w = wr[k];
            acc0 += feat[k] * w;
            acc1 += feat[2048 + k] * w;
        }
        __syncthreads();
    }
    xs[tid]       = fminf(fmaxf(acc0 + b_in[tid], 0.f), 1.f);
    xs[256 + tid] = fminf(fmaxf(acc1 + b_in[tid], 0.f), 1.f);
    __syncthreads();
    if (tid < 32) {
        float a = b_h1[tid];
        for (int j = 0; j < 512; ++j) a += xs[j] * w_h1[tid * 512 + j];
        h1s[tid] = fminf(fmaxf(a, 0.f), 1.f);
    }
    __syncthreads();
    if (tid < 32) {
        float a = b_h2[tid];
        for (int j = 0; j < 32; ++j) a += h1s[j] * w_h2[tid * 32 + j];
        h2s[tid] = fminf(fmaxf(a, 0.f), 1.f);
    }
    __syncthreads();
    if (tid == 0) {
        float a = b_out[0];
        for (int j = 0; j < 32; ++j) a += h2s[j] * w_out[j];
        out[b] = a;
    }
}

extern "C" void kernel_launch(void* const* d_in, const int* in_sizes, int n_in,
                              void* d_out, int out_size, void* d_ws, size_t ws_size,
                              hipStream_t stream)
{
    const float* white = (const float*)d_in[0];
    const float* black = (const float*)d_in[1];
    const float* w_in  = (const float*)d_in[2];
    const float* b_in  = (const float*)d_in[3];
    const float* w_h1  = (const float*)d_in[4];
    const float* b_h1  = (const float*)d_in[5];
    const float* w_h2  = (const float*)d_in[6];
    const float* b_h2  = (const float*)d_in[7];
    const float* w_out = (const float*)d_in[8];
    const float* b_out = (const float*)d_in[9];
    float* out = (float*)d_out;

    const size_t f32Need = KSPLIT * PSTRIDE * sizeof(float);     // 64 MB
    const size_t f16Need = KSPLIT * PSTRIDE * sizeof(_Float16);  // 32 MB

    if (ws_size >= f32Need) {
        float* P = (float*)d_ws;
        nnue_gemm8<float><<<dim3(64 * KSPLIT), 512, 0, stream>>>(white, black, w_in, P);
        nnue_tail8<float><<<dim3(128), 256, 0, stream>>>(P, b_in, w_h1, b_h1,
                                                         w_h2, b_h2, w_out, b_out, out);
    } else if (ws_size >= f16Need) {
        _Float16* P = (_Float16*)d_ws;
        nnue_gemm8<_Float16><<<dim3(64 * KSPLIT), 512, 0, stream>>>(white, black, w_in, P);
        nnue_tail8<_Float16><<<dim3(128), 256, 0, stream>>>(P, b_in, w_h1, b_h1,
                                                            w_h2, b_h2, w_out, b_out, out);
    } else {
        nnue_naive<<<4096, 256, 0, stream>>>(white, black, w_in, b_in, w_h1, b_h1,
                                             w_h2, b_h2, w_out, b_out, out);
    }
}

// Round 4
// 397.229 us; speedup vs baseline: 1.6388x; 1.0523x over previous
//
#include <hip/hip_runtime.h>
#include <hip/hip_fp16.h>

// NNUE forward: out = MLP(clip(concat(Wf@w_in^T+b, Bf@w_in^T+b)))
// Big GEMM: M=8192, N=256, K=40960. Memory-bound: ~1.38 GB mandatory reads.
// fp16 MFMA 16x16x32, f32 accumulate, f32->f16 cvt fused into LDS staging.
//
// v4 (from r3 counters: 2.1e7 bank conflicts, 2-barrier serialization):
//  - conflict-free XOR swizzle ((row>>1)&3)<<4  (r3's (row&3)<<4 was 4-way)
//  - double-buffered LDS, ONE barrier per K-step:
//      mfma(buf) || cvtStore(buf^1, regs from t-1) || issue(t+1) ; barrier
//  - geometry unchanged: BM=128 BN=256 BK=32, 512 thr, KS=8 -> 512 blocks, 2/CU

#define FEAT 40960
#define PSTRIDE (8192ull * 256ull)
#define KSPLIT 8
#define KCHUNK (FEAT / KSPLIT)   // 5120
#define NSTEPS (KCHUNK / 32)     // 160

using floatx4 = __attribute__((ext_vector_type(4))) float;
using half8   = __attribute__((ext_vector_type(8))) _Float16;
using half4   = __attribute__((ext_vector_type(4))) _Float16;

// ---------------------------------------------------------------------------
// GEMM: 512 threads = 8 waves (2M x 4N), wave tile 64x64 (acc 4x4 = 64 regs).
// ---------------------------------------------------------------------------
template <typename PT>
__global__ __launch_bounds__(512, 4) void nnue_gemm8(
    const float* __restrict__ white, const float* __restrict__ black,
    const float* __restrict__ w_in, PT* __restrict__ P)
{
    __shared__ __align__(16) _Float16 As[2][128 * 32];   // 16 KB
    __shared__ __align__(16) _Float16 Ws[2][256 * 32];   // 32 KB

    const int tid  = threadIdx.x;
    const int lane = tid & 63;
    const int wave = tid >> 6;    // 0..7
    const int wm   = wave >> 2;   // 0..1 (M)
    const int wn   = wave & 3;    // 0..3 (N)

    const int mb = blockIdx.x & 63;
    const int ks = blockIdx.x >> 6;

    const float* Abase = (mb < 32)
        ? (white + (size_t)mb * 128 * FEAT)
        : (black + (size_t)(mb - 32) * 128 * FEAT);
    const int k0 = ks * KCHUNK;

    // staging: A tile 128x32 f32 (2 float4/thread), W 256x32 (4 float4/thread)
    const int c4    = tid & 7;               // float4 column (8 per row)
    const int row0  = tid >> 3;              // 0..63
    // conflict-free involution: XOR bits 4..5 of the byte offset with (row>>1)&3.
    // rows row0 and row0+64 share (row>>1)&3? (row0+64)>>1 = row0>>1 + 32 -> &3 equal. yes.
    const int swz_w = ((row0 >> 1) & 3) << 4;
    const int woff  = (c4 * 8) ^ swz_w;

    // fragment geometry (mfma_f32_16x16x32_f16):
    // operand: lane reads row (lane&15), k-halves (lane>>4)*8..+7 (16B)
    // C/D:     row = (lane>>4)*4 + reg, col = lane&15
    const int frow  = lane & 15;
    const int fhi   = lane >> 4;
    const int swz_r = ((frow >> 1) & 3) << 4;
    const int kb    = (fhi * 16) ^ swz_r;    // byte offset within 64B row

    floatx4 acc[4][4];
    const floatx4 zero = {0.f, 0.f, 0.f, 0.f};
#pragma unroll
    for (int m = 0; m < 4; ++m)
#pragma unroll
        for (int n = 0; n < 4; ++n) acc[m][n] = zero;

    floatx4 ra[2], rw[4];

    auto issue = [&](int kglob) {
#pragma unroll
        for (int i = 0; i < 2; ++i)
            ra[i] = *reinterpret_cast<const floatx4*>(
                Abase + (size_t)(row0 + 64 * i) * FEAT + kglob + c4 * 4);
#pragma unroll
        for (int i = 0; i < 4; ++i)
            rw[i] = *reinterpret_cast<const floatx4*>(
                w_in + (size_t)(row0 + 64 * i) * FEAT + kglob + c4 * 4);
    };

    auto cvtStore = [&](int buf) {
#pragma unroll
        for (int i = 0; i < 2; ++i) {
            half4 h;
#pragma unroll
            for (int j = 0; j < 4; ++j) h[j] = (_Float16)ra[i][j];   // RNE
            *reinterpret_cast<half4*>(
                reinterpret_cast<char*>(&As[buf][0]) + (row0 + 64 * i) * 64 + woff) = h;
        }
#pragma unroll
        for (int i = 0; i < 4; ++i) {
            half4 h;
#pragma unroll
            for (int j = 0; j < 4; ++j) h[j] = (_Float16)rw[i][j];
            *reinterpret_cast<half4*>(
                reinterpret_cast<char*>(&Ws[buf][0]) + (row0 + 64 * i) * 64 + woff) = h;
        }
    };

    auto mfmaStep = [&](int buf) {
        half8 bf[4];
#pragma unroll
        for (int n = 0; n < 4; ++n) {
            const int r = wn * 64 + n * 16 + frow;
            bf[n] = *reinterpret_cast<const half8*>(
                reinterpret_cast<const char*>(&Ws[buf][0]) + r * 64 + kb);
        }
#pragma unroll
        for (int m = 0; m < 4; ++m) {
            const int r = wm * 64 + m * 16 + frow;
            half8 af = *reinterpret_cast<const half8*>(
                reinterpret_cast<const char*>(&As[buf][0]) + r * 64 + kb);
#pragma unroll
            for (int n = 0; n < 4; ++n)
                acc[m][n] = __builtin_amdgcn_mfma_f32_16x16x32_f16(af, bf[n], acc[m][n], 0, 0, 0);
        }
    };

    // prologue: tile 0 -> buf0, tile 1 in flight
    issue(k0);
    cvtStore(0);
    issue(k0 + 32);
    __syncthreads();

    // steady state: one barrier per step.
    //   mfma(buf t) first in program order (doesn't wait on vmcnt);
    //   cvtStore(buf t+1) waits on loads issued at t-1 (one full step in flight);
    //   issue(t+2) refills.
    for (int t = 0; t < NSTEPS; ++t) {
        mfmaStep(t & 1);
        if (t + 1 < NSTEPS) {
            cvtStore((t + 1) & 1);
            if (t + 2 < NSTEPS) issue(k0 + (t + 2) * 32);
        }
        __syncthreads();
    }

    // epilogue: partial C (pre-bias, pre-clip) to workspace
    PT* Pb = P + (size_t)ks * PSTRIDE + (size_t)mb * 128 * 256;
#pragma unroll
    for (int m = 0; m < 4; ++m)
#pragma unroll
        for (int n = 0; n < 4; ++n)
#pragma unroll
            for (int r = 0; r < 4; ++r) {
                const int row = wm * 64 + m * 16 + fhi * 4 + r;
                const int col = wn * 64 + n * 16 + frow;
                Pb[(size_t)row * 256 + col] = (PT)acc[m][n][r];
            }
}

// ---------------------------------------------------------------------------
// Tail: reduce 8 K-split partials + b_in + clip -> x[.,512], then the 3 tiny
// layers. One block per 32 batch rows.
// ---------------------------------------------------------------------------
template <typename PT>
__global__ __launch_bounds__(256) void nnue_tail8(
    const PT* __restrict__ P,
    const float* __restrict__ b_in,
    const float* __restrict__ w_h1, const float* __restrict__ b_h1,
    const float* __restrict__ w_h2, const float* __restrict__ b_h2,
    const float* __restrict__ w_out, const float* __restrict__ b_out,
    float* __restrict__ out)
{
    __shared__ float xs[32][512];
    __shared__ float w1[32][513];
    __shared__ float w2[32][33];
    __shared__ float h1[32][33];
    __shared__ float h2[32][33];
    __shared__ float wo[32];

    const int tid = threadIdx.x;
    const int b0  = blockIdx.x * 32;

    for (int i = tid; i < 32 * 512; i += 256) w1[i >> 9][i & 511] = w_h1[i];
    for (int i = tid; i < 32 * 32; i += 256)  w2[i >> 5][i & 31]  = w_h2[i];
    if (tid < 32) wo[tid] = w_out[tid];

    for (int i = tid; i < 32 * 512; i += 256) {
        const int r = i >> 9, c = i & 511;
        const int persp = c >> 8, n = c & 255;
        const size_t prow = (size_t)(b0 + r) + (persp ? 4096u : 0u);
        float v = 0.f;
#pragma unroll
        for (int s = 0; s < KSPLIT; ++s)
            v += (float)P[(size_t)s * PSTRIDE + prow * 256 + n];
        v += b_in[n];
        xs[r][c] = fminf(fmaxf(v, 0.f), 1.f);
    }
    __syncthreads();

    for (int p = tid; p < 32 * 32; p += 256) {
        const int o = p & 31, r = p >> 5;
        float a = b_h1[o];
        for (int j = 0; j < 512; ++j) a += xs[r][j] * w1[o][j];
        h1[r][o] = fminf(fmaxf(a, 0.f), 1.f);
    }
    __syncthreads();

    for (int p = tid; p < 32 * 32; p += 256) {
        const int o = p & 31, r = p >> 5;
        float a = b_h2[o];
        for (int j = 0; j < 32; ++j) a += h1[r][j] * w2[o][j];
        h2[r][o] = fminf(fmaxf(a, 0.f), 1.f);
    }
    __syncthreads();

    if (tid < 32) {
        float a = b_out[0];
        for (int j = 0; j < 32; ++j) a += h2[tid][j] * wo[j];
        out[b0 + tid] = a;
    }
}

// ---------------------------------------------------------------------------
// Emergency fallback (ws too small for any split): slow but correct.
// ---------------------------------------------------------------------------
__global__ __launch_bounds__(256) void nnue_naive(
    const float* __restrict__ white, const float* __restrict__ black,
    const float* __restrict__ w_in, const float* __restrict__ b_in,
    const float* __restrict__ w_h1, const float* __restrict__ b_h1,
    const float* __restrict__ w_h2, const float* __restrict__ b_h2,
    const float* __restrict__ w_out, const float* __restrict__ b_out,
    float* __restrict__ out)
{
    __shared__ float feat[4096];
    __shared__ float xs[512];
    __shared__ float h1s[32];
    __shared__ float h2s[32];
    const int b = blockIdx.x, tid = threadIdx.x;
    float acc0 = 0.f, acc1 = 0.f;
    for (int c = 0; c < FEAT; c += 2048) {
        for (int i = tid; i < 2048; i += 256) {
            feat[i]        = white[(size_t)b * FEAT + c + i];
            feat[2048 + i] = black[(size_t)b * FEAT + c + i];
        }
        __syncthreads();
        const float* wr = w_in + (size_t)tid * FEAT + c;
        for (int k = 0; k < 2048; ++k) {
            const float w = wr[k];
            acc0 += feat[k] * w;
            acc1 += feat[2048 + k] * w;
        }
        __syncthreads();
    }
    xs[tid]       = fminf(fmaxf(acc0 + b_in[tid], 0.f), 1.f);
    xs[256 + tid] = fminf(fmaxf(acc1 + b_in[tid], 0.f), 1.f);
    __syncthreads();
    if (tid < 32) {
        float a = b_h1[tid];
        for (int j = 0; j < 512; ++j) a += xs[j] * w_h1[tid * 512 + j];
        h1s[tid] = fminf(fmaxf(a, 0.f), 1.f);
    }
    __syncthreads();
    if (tid < 32) {
        float a = b_h2[tid];
        for (int j = 0; j < 32; ++j) a += h1s[j] * w_h2[tid * 32 + j];
        h2s[tid] = fminf(fmaxf(a, 0.f), 1.f);
    }
    __syncthreads();
    if (tid == 0) {
        float a = b_out[0];
        for (int j = 0; j < 32; ++j) a += h2s[j] * w_out[j];
        out[b] = a;
    }
}

extern "C" void kernel_launch(void* const* d_in, const int* in_sizes, int n_in,
                              void* d_out, int out_size, void* d_ws, size_t ws_size,
                              hipStream_t stream)
{
    const float* white = (const float*)d_in[0];
    const float* black = (const float*)d_in[1];
    const float* w_in  = (const float*)d_in[2];
    const float* b_in  = (const float*)d_in[3];
    const float* w_h1  = (const float*)d_in[4];
    const float* b_h1  = (const float*)d_in[5];
    const float* w_h2  = (const float*)d_in[6];
    const float* b_h2  = (const float*)d_in[7];
    const float* w_out = (const float*)d_in[8];
    const float* b_out = (const float*)d_in[9];
    float* out = (float*)d_out;

    const size_t f32Need = KSPLIT * PSTRIDE * sizeof(float);     // 64 MB
    const size_t f16Need = KSPLIT * PSTRIDE * sizeof(_Float16);  // 32 MB

    if (ws_size >= f32Need) {
        float* P = (float*)d_ws;
        nnue_gemm8<float><<<dim3(64 * KSPLIT), 512, 0, stream>>>(white, black, w_in, P);
        nnue_tail8<float><<<dim3(128), 256, 0, stream>>>(P, b_in, w_h1, b_h1,
                                                         w_h2, b_h2, w_out, b_out, out);
    } else if (ws_size >= f16Need) {
        _Float16* P = (_Float16*)d_ws;
        nnue_gemm8<_Float16><<<dim3(64 * KSPLIT), 512, 0, stream>>>(white, black, w_in, P);
        nnue_tail8<_Float16><<<dim3(128), 256, 0, stream>>>(P, b_in, w_h1, b_h1,
                                                            w_h2, b_h2, w_out, b_out, out);
    } else {
        nnue_naive<<<4096, 256, 0, stream>>>(white, black, w_in, b_in, w_h1, b_h1,
                                             w_h2, b_h2, w_out, b_out, out);
    }
}